// Round 14
// baseline (364.855 us; speedup 1.0000x reference)
//
#include <hip/hip_runtime.h>
#include <math.h>

#define IMN 1024
#define IMGSZ (IMN * IMN)
#define NIMG 6
#define EPSV 0.001f
#define NB1 4096

typedef unsigned short u16;
typedef _Float16 f16;
typedef __attribute__((ext_vector_type(8))) _Float16 half8;   // 8 f16 = 4 VGPRs
typedef __attribute__((ext_vector_type(16))) float floatx16;  // 32x32 C/D

__device__ __forceinline__ u16 f16_bits(float v) {
  union { f16 h; u16 b; } u;
  u.h = (f16)v;  // v_cvt_f16_f32, RNE
  return u.b;
}
__device__ __forceinline__ float f16_val(u16 b) {
  union { f16 h; u16 b2; } u;
  u.b2 = b;
  return (float)u.h;
}
__device__ __forceinline__ void unp4(uint2 v, float* o) {
  o[0] = f16_val((u16)(v.x & 0xffff));
  o[1] = f16_val((u16)(v.x >> 16));
  o[2] = f16_val((u16)(v.y & 0xffff));
  o[3] = f16_val((u16)(v.y >> 16));
}

// ---------------------------------------------------------------------------
// ONE prep dispatch replaces build_taps + 3x build_w + split_img.  grid (1024,4):
//   y in 0..2: scale y.  Taps computed INLINE (same expf inputs, same strided
//     accumulation + tree reduction order as the old build_taps -> inv is
//     bit-identical; W row = atomicAdd of v*inv, identical to before).
//     W' = 256*W stored f16 (normal range; pow2 unscaled in EPI=1).
//     Band support (exact): support(W[r,.]) c [max(0,r-p), min(1023,r+p)];
//     outside it W' is exact 0.0 -> gemm skips those K ranges bit-exactly.
//   y == 3: split_img (6 row-sweeps) + writes logI = f16 log(max(inp,eps))
//     (loss1 then needs NO logf and reads 12MB f16 instead of 24MB fp32);
//     block 0 zeroes out[0..2] for the atomic loss finale (no fence/counter
//     -- round-11 lesson: per-block __threadfence serializes to 182us;
//     plain device-scope atomicAdd does not).
__global__ __launch_bounds__(256) void prep_k(const float* __restrict__ inp,
                                              u16* __restrict__ H,
                                              u16* __restrict__ LI,
                                              u16* __restrict__ WF,
                                              float* __restrict__ out) {
  int y = blockIdx.y;
  int tid = threadIdx.x;
  if (y == 3) {
    if (blockIdx.x == 0 && tid == 0) {
      out[0] = 0.f;
      out[1] = 0.f;
      out[2] = 0.f;
    }
#pragma unroll
    for (int r2 = 0; r2 < 6; r2++) {
      int i4 = ((r2 * 1024 + blockIdx.x) << 10) + tid * 4;
      float4 v = *(const float4*)&inp[i4];
      float x[4] = {v.x, v.y, v.z, v.w};
      u16 h[4], l[4];
#pragma unroll
      for (int e = 0; e < 4; e++) {
        h[e] = f16_bits(fminf(fmaxf(x[e], EPSV), 1.f));
        l[e] = f16_bits(logf(fmaxf(x[e], EPSV)));
      }
      *(uint2*)&H[i4] = make_uint2((unsigned)h[0] | ((unsigned)h[1] << 16),
                                   (unsigned)h[2] | ((unsigned)h[3] << 16));
      *(uint2*)&LI[i4] = make_uint2((unsigned)l[0] | ((unsigned)l[1] << 16),
                                    (unsigned)l[2] | ((unsigned)l[3] << 16));
    }
    return;
  }
  const int kss[3] = {91, 481, 1501};
  const float sg[3] = {15.f, 80.f, 250.f};
  int ks = kss[y];
  float sigma = sg[y];
  int r = blockIdx.x;
  int p = ks >> 1;
  float ctr = (float)(ks - 1) * 0.5f;
  __shared__ float red[256];
  __shared__ float row[IMN];
  float loc = 0.f;
  for (int t = tid; t < ks; t += 256) {
    float x = ((float)t - ctr) / sigma;
    loc += expf(-0.5f * x * x);
  }
  red[tid] = loc;
  __syncthreads();
  for (int o = 128; o > 0; o >>= 1) {
    if (tid < o) red[tid] += red[tid + o];
    __syncthreads();
  }
  float inv = 1.f / red[0];
  for (int i2 = tid; i2 < IMN; i2 += 256) row[i2] = 0.f;
  __syncthreads();
  for (int t = tid; t < ks; t += 256) {
    float x = ((float)t - ctr) / sigma;
    float v = expf(-0.5f * x * x) * inv;
    int q = r + t - p;
    int j = q < 0 ? -q : (q > IMN - 1 ? 2 * (IMN - 1) - q : q);
    atomicAdd(&row[j], v);
  }
  __syncthreads();
  for (int i2 = tid; i2 < IMN; i2 += 256)
    WF[(size_t)y * IMGSZ + (size_t)r * IMN + i2] = f16_bits(row[i2] * 256.f);
}

// ---------------------------------------------------------------------------
// f16 MFMA GEMM (A x W'), 128x128 tile, 32x32x16_f16, wave 64x64.
// EXACT round-10/12 gemm (best measured: 58.3us/gemm; k-loop is closed -- 4
//   structurally different schedules all land 61-67us pre-f16; latency floor).
// Band-limited K loop (exact; see prep_k note).
// Structure lessons kept: (256,4) reg-staging (r3: (256,6)+no-barrier spills;
//   r5: A-direct regresses; r2/r8: gload_lds/counted-vmcnt neutral-worse).
//   LDS linear [128][32] + both-sides XOR swizzle (r4-verified):
//   phys_slot = slot ^ ((row>>1)&3) at ds_write AND ds_read.
// EPI=0: A = imgF[i], B = W'[s]; out OH[z] = f16 U' = 256*U, transposed.
// EPI=1: A = UtH[z],  B = W'[s]; out LB16 = f16 log(max(acc*2^-16, eps)).
template <int EPI>
__global__ __launch_bounds__(256, 4) void gemm_pass(
    const u16* __restrict__ AH, const u16* __restrict__ WF,
    u16* __restrict__ OH, u16* __restrict__ LB16, int sBase, int outByZ, int rmw) {
  __shared__ u16 smem[2 * 128 * 32 + 256];  // 16896 B (B tiles 16384; epi scratch 16896)
  u16* Af = smem;
  u16* Bf = smem + 128 * 32;
  int z = blockIdx.z;
  int zs = z / 6;
  int s = (gridDim.z >= 18) ? (sBase + 2 - zs) : (sBase + zs);  // heavy-first
  int i = z - zs * 6;
  const u16* Ag = AH + (size_t)(EPI == 0 ? i : z) * IMGSZ;
  const u16* Bg = WF + (size_t)s * IMGSZ;
  int bm = blockIdx.y * 128, bn = blockIdx.x * 128;
  int tid = threadIdx.x;
  int lane = tid & 63, w = tid >> 6;
  int wm = (w >> 1) * 64, wn = (w & 1) * 64;
  int lrow = lane & 31, lh = lane >> 5;
  int sig = (lrow >> 1) & 3;              // frag-read swizzle key
  int tr = tid >> 2;                      // staging row 0..63 (and +64)
  int tc = (tid & 3) * 8;                 // linear global col offset (u16)
  int sslot = ((tid & 3) ^ ((tr >> 1) & 3)) * 8;  // swizzled LDS slot offset
  floatx16 acc[2][2] = {};

  // Band-limited K window (exact: W' is 0.0 outside).
  int p = (s == 0) ? 45 : (s == 1) ? 240 : 750;
  int klo = bn - p;
  klo = (klo < 0 ? 0 : klo) & ~31;
  int khi = bn + 128 + p;
  if (khi > IMN) khi = IMN;

  for (int k0 = klo; k0 < khi; k0 += 32) {
    uint4 a0 = *(const uint4*)&Ag[(size_t)(bm + tr) * IMN + k0 + tc];
    uint4 a1 = *(const uint4*)&Ag[(size_t)(bm + tr + 64) * IMN + k0 + tc];
    uint4 b0 = *(const uint4*)&Bg[(size_t)(bn + tr) * IMN + k0 + tc];
    uint4 b1 = *(const uint4*)&Bg[(size_t)(bn + tr + 64) * IMN + k0 + tc];
    *(uint4*)&Af[tr * 32 + sslot] = a0;
    *(uint4*)&Af[(tr + 64) * 32 + sslot] = a1;
    *(uint4*)&Bf[tr * 32 + sslot] = b0;
    *(uint4*)&Bf[(tr + 64) * 32 + sslot] = b1;
    __syncthreads();
#pragma unroll
    for (int kk = 0; kk < 32; kk += 16) {
      int sl = (kk >> 3) + lh;            // logical 16B slot 0..3
      int so = ((sl ^ sig) * 8);          // swizzled read offset (u16)
      half8 ah[2], bh[2];
#pragma unroll
      for (int mt = 0; mt < 2; mt++)
        ah[mt] = *(const half8*)&Af[(wm + mt * 32 + lrow) * 32 + so];
#pragma unroll
      for (int nt2 = 0; nt2 < 2; nt2++)
        bh[nt2] = *(const half8*)&Bf[(wn + nt2 * 32 + lrow) * 32 + so];
#pragma unroll
      for (int mt = 0; mt < 2; mt++)
#pragma unroll
        for (int nt2 = 0; nt2 < 2; nt2++)
          acc[mt][nt2] = __builtin_amdgcn_mfma_f32_32x32x16_f16(ah[mt], bh[nt2], acc[mt][nt2], 0, 0, 0);
    }
    __syncthreads();
  }

  // Epilogue: per-wave 32x32 LDS transpose (stride 33), coalesced row stores.
  // C/D: col(n)=lane&31, row(m)=(reg&3)+8*(reg>>2)+4*(lane>>5).
  float* lf = (float*)smem + w * 1056;  // 4 x 4224 B = 16896 B total
#pragma unroll
  for (int mt = 0; mt < 2; mt++)
#pragma unroll
    for (int nt = 0; nt < 2; nt++) {
#pragma unroll
      for (int rq = 0; rq < 4; rq++)
#pragma unroll
        for (int e = 0; e < 4; e++)
          lf[lrow * 33 + rq * 8 + lh * 4 + e] = acc[mt][nt][rq * 4 + e];
      __syncthreads();
#pragma unroll
      for (int p4 = 0; p4 < 4; p4++) {
        int rl = p4 * 8 + (lane >> 3);
        int cl = (lane & 7) * 4;
        float v0 = lf[rl * 33 + cl + 0];
        float v1 = lf[rl * 33 + cl + 1];
        float v2 = lf[rl * 33 + cl + 2];
        float v3 = lf[rl * 33 + cl + 3];
        int gn = bn + wn + nt * 32 + rl;  // output row
        int gm = bm + wm + mt * 32 + cl;  // output col
        if (EPI == 0) {
          // acc IS U' = 256*U; store f16 (values in [0.256, 256]).
          size_t go = (size_t)z * IMGSZ + (size_t)gn * IMN + gm;  // keep plane offset!
          *(uint2*)&OH[go] = make_uint2(
              (unsigned)f16_bits(v0) | ((unsigned)f16_bits(v1) << 16),
              (unsigned)f16_bits(v2) | ((unsigned)f16_bits(v3) << 16));
        } else {
          // acc = 65536*blur2; un-scale exactly (pow2), log, store f16.
          const float us = 0x1p-16f;
          size_t go = (size_t)(outByZ ? z : i) * IMGSZ + (size_t)gn * IMN + gm;
          float r0 = logf(fmaxf(v0 * us, EPSV));
          float r1 = logf(fmaxf(v1 * us, EPSV));
          float r2 = logf(fmaxf(v2 * us, EPSV));
          float r3 = logf(fmaxf(v3 * us, EPSV));
          if (rmw) {  // t2 fallback: accumulate in f16 (tolerance-safe)
            uint2 pa = *(const uint2*)&LB16[go];
            float o4[4];
            unp4(pa, o4);
            r0 += o4[0]; r1 += o4[1]; r2 += o4[2]; r3 += o4[3];
          }
          *(uint2*)&LB16[go] = make_uint2(
              (unsigned)f16_bits(r0) | ((unsigned)f16_bits(r1) << 16),
              (unsigned)f16_bits(r2) | ((unsigned)f16_bits(r3) << 16));
        }
      }
      __syncthreads();
    }
}

// ---------------------------------------------------------------------------
// Vectorized 4-pixel chunks (G13): uint2 f16 lb/LI loads, NO logf (LI is
// precomputed f16 log(max(inp,eps)) from prep_k).  refl/illum = out+3 ->
// 12B offset: stores MUST be scalar dwords (round-9 float4 there = GPU fault).
// Finale: per-block atomicAdd into out[0..2] (zeroed by prep_k).  NO
// __threadfence, NO counter -- round-11 lesson: the fence (L2 writeback on
// non-coherent XCD L2s) serialized this kernel to 182us; plain device-scope
// atomicAdd is cheap (3 atomics/block x 4096 blocks, m20/G12).
__global__ __launch_bounds__(256) void loss_stage1_k(const u16* __restrict__ li,
                                                     const u16* __restrict__ lb, int three,
                                                     float* __restrict__ refl,
                                                     float* __restrict__ illum,
                                                     float* __restrict__ out) {
  const int S = NIMG * IMGSZ;
  const int NCH = S >> 2;
  const int stride = NB1 * 256;
  const float third = 1.f / 3.f;
  float sd = 0.f, ss = 0.f;
  for (int c = blockIdx.x * 256 + threadIdx.x; c < NCH; c += stride) {
    int i = c << 2;
    int col = i & (IMN - 1);            // multiple of 4
    int row = (i >> 10) & (IMN - 1);
    bool hR = col < (IMN - 4);
    bool hD = row < (IMN - 1);
    float sum[5];
    {
      float t0[4];
      unp4(*(const uint2*)&lb[i], t0);
      sum[0] = t0[0]; sum[1] = t0[1]; sum[2] = t0[2]; sum[3] = t0[3];
      sum[4] = hR ? f16_val(lb[i + 4]) : 0.f;
      if (three) {
        float t1[4], t2[4];
        unp4(*(const uint2*)&lb[i + S], t1);
        unp4(*(const uint2*)&lb[i + 2 * S], t2);
#pragma unroll
        for (int j = 0; j < 4; j++) sum[j] += t1[j] + t2[j];
        if (hR) sum[4] += f16_val(lb[i + 4 + S]) + f16_val(lb[i + 4 + 2 * S]);
      }
    }
    float Iv[5], Rv[5], LIv[4];
#pragma unroll
    for (int j = 0; j < 5; j++) Iv[j] = sum[j] * third;
    unp4(*(const uint2*)&li[i], LIv);
#pragma unroll
    for (int j = 0; j < 4; j++) Rv[j] = LIv[j] - Iv[j];
    if (hR) Rv[4] = f16_val(li[i + 4]) - Iv[4];
#pragma unroll
    for (int j = 0; j < 4; j++) {  // scalar stores: refl/illum are 12B-offset
      refl[i + j] = Rv[j];
      illum[i + j] = Iv[j];
    }
#pragma unroll
    for (int j = 0; j < 3; j++) {
      sd += fabsf(Rv[j] - Rv[j + 1]);
      ss += fabsf(Iv[j] - Iv[j + 1]);
    }
    if (hR) {
      sd += fabsf(Rv[3] - Rv[4]);
      ss += fabsf(Iv[3] - Iv[4]);
    }
    if (hD) {
      int ib = i + IMN;
      float sb[4];
      {
        float t0[4];
        unp4(*(const uint2*)&lb[ib], t0);
        sb[0] = t0[0]; sb[1] = t0[1]; sb[2] = t0[2]; sb[3] = t0[3];
        if (three) {
          float t1[4], t2[4];
          unp4(*(const uint2*)&lb[ib + S], t1);
          unp4(*(const uint2*)&lb[ib + 2 * S], t2);
#pragma unroll
          for (int j = 0; j < 4; j++) sb[j] += t1[j] + t2[j];
        }
      }
      float LBv[4];
      unp4(*(const uint2*)&li[ib], LBv);
#pragma unroll
      for (int j = 0; j < 4; j++) {
        float Ib = sb[j] * third;
        float Rb = LBv[j] - Ib;
        sd += fabsf(Rv[j] - Rb);
        ss += fabsf(Iv[j] - Ib);
      }
    }
  }
  for (int o = 32; o > 0; o >>= 1) {
    sd += __shfl_down(sd, o);
    ss += __shfl_down(ss, o);
  }
  __shared__ float rsd[4], rss[4];
  int lane = threadIdx.x & 63, w = threadIdx.x >> 6;
  if (lane == 0) { rsd[w] = sd; rss[w] = ss; }
  __syncthreads();
  if (threadIdx.x == 0) {
    const float sc = 1.f / 6285312.f;  // 2*3*1024*1023
    float bsd = (rsd[0] + rsd[1] + rsd[2] + rsd[3]) * sc;
    float bss = (rss[0] + rss[1] + rss[2] + rss[3]) * sc;
    atomicAdd(&out[0], bss);
    atomicAdd(&out[1], bsd);
    atomicAdd(&out[2], bss);
  }
}

// ---------------------------------------------------------------------------
extern "C" void kernel_launch(void* const* d_in, const int* in_sizes, int n_in,
                              void* d_out, int out_size, void* d_ws, size_t ws_size,
                              hipStream_t stream) {
  const float* inp = (const float*)d_in[0];
  float* out = (float*)d_out;
  float* refl = out + 3;
  float* illum = refl + (size_t)NIMG * IMGSZ;

  char* p = (char*)d_ws;
  u16* WF = (u16*)p;                        p += (size_t)3 * IMGSZ * 2;
  u16* imgF = (u16*)p;                      p += (size_t)NIMG * IMGSZ * 2;
  u16* logI = (u16*)p;                      p += (size_t)NIMG * IMGSZ * 2;
  size_t fixed = (size_t)(p - (char*)d_ws);
  // Tier1 (z=18, one dispatch/pass): Ut 18 f16 planes (36 MB) + LB 18 f16
  // (36 MB).  Total ~102 MB; ws_size >= 132 MB proven by rounds 0-1 (tier1
  // ran with a 132 MB layout), so tier1 is guaranteed here.
  size_t needT1 = fixed + (size_t)18 * IMGSZ * 2 + (size_t)18 * IMGSZ * 2;
  bool t1 = ws_size >= needT1;
  int nz = t1 ? 18 : 6;
  u16* UtH = (u16*)p;                       p += (size_t)nz * IMGSZ * 2;
  u16* LB = (u16*)p;  // t1: 18 f16 log-blur planes; t2: 6-plane f16 accumulator

  prep_k<<<dim3(1024, 4), 256, 0, stream>>>(inp, imgF, logI, WF, out);

  if (t1) {
    dim3 g(8, 8, 18);
    gemm_pass<0><<<g, 256, 0, stream>>>(imgF, WF, UtH, nullptr, 0, 1, 0);
    gemm_pass<1><<<g, 256, 0, stream>>>(UtH, WF, nullptr, LB, 0, 1, 0);
  } else {
    dim3 g(8, 8, 6);
    for (int s = 0; s < 3; s++) {
      gemm_pass<0><<<g, 256, 0, stream>>>(imgF, WF, UtH, nullptr, s, 0, 0);
      gemm_pass<1><<<g, 256, 0, stream>>>(UtH, WF, nullptr, LB, s, 0, s > 0);
    }
  }
  loss_stage1_k<<<NB1, 256, 0, stream>>>(logI, LB, t1 ? 1 : 0, refl, illum, out);
}

// Round 15
// 223.868 us; speedup vs baseline: 1.6298x; 1.6298x over previous
//
#include <hip/hip_runtime.h>
#include <math.h>

#define IMN 1024
#define IMGSZ (IMN * IMN)
#define NIMG 6
#define EPSV 0.001f
#define NB1 4096

typedef unsigned short u16;
typedef _Float16 f16;
typedef __attribute__((ext_vector_type(8))) _Float16 half8;   // 8 f16 = 4 VGPRs
typedef __attribute__((ext_vector_type(16))) float floatx16;  // 32x32 C/D

__device__ __forceinline__ u16 f16_bits(float v) {
  union { f16 h; u16 b; } u;
  u.h = (f16)v;  // v_cvt_f16_f32, RNE
  return u.b;
}
__device__ __forceinline__ float f16_val(u16 b) {
  union { f16 h; u16 b2; } u;
  u.b2 = b;
  return (float)u.h;
}
__device__ __forceinline__ void unp4(uint2 v, float* o) {
  o[0] = f16_val((u16)(v.x & 0xffff));
  o[1] = f16_val((u16)(v.x >> 16));
  o[2] = f16_val((u16)(v.y & 0xffff));
  o[3] = f16_val((u16)(v.y >> 16));
}

// ---------------------------------------------------------------------------
// ONE prep dispatch replaces build_taps + 3x build_w + split_img.  grid (1024,4):
//   y in 0..2: scale y.  Taps computed INLINE (same expf inputs, same strided
//     accumulation + tree reduction order as the old build_taps -> inv is
//     bit-identical; W row = atomicAdd of v*inv, identical to before).
//     W' = 256*W stored f16 (normal range; pow2 unscaled in EPI=1).
//     Band support (exact): support(W[r,.]) c [max(0,r-p), min(1023,r+p)];
//     outside it W' is exact 0.0 -> gemm skips those K ranges bit-exactly.
//   y == 3: split_img (6 row-sweeps) + writes logI = f16 log(max(inp,eps))
//     so loss1 needs NO logf and reads 12MB f16 instead of 24MB fp32.
__global__ __launch_bounds__(256) void prep_k(const float* __restrict__ inp,
                                              u16* __restrict__ H,
                                              u16* __restrict__ LI,
                                              u16* __restrict__ WF) {
  int y = blockIdx.y;
  int tid = threadIdx.x;
  if (y == 3) {
#pragma unroll
    for (int r2 = 0; r2 < 6; r2++) {
      int i4 = ((r2 * 1024 + blockIdx.x) << 10) + tid * 4;
      float4 v = *(const float4*)&inp[i4];
      float x[4] = {v.x, v.y, v.z, v.w};
      u16 h[4], l[4];
#pragma unroll
      for (int e = 0; e < 4; e++) {
        h[e] = f16_bits(fminf(fmaxf(x[e], EPSV), 1.f));
        l[e] = f16_bits(logf(fmaxf(x[e], EPSV)));
      }
      *(uint2*)&H[i4] = make_uint2((unsigned)h[0] | ((unsigned)h[1] << 16),
                                   (unsigned)h[2] | ((unsigned)h[3] << 16));
      *(uint2*)&LI[i4] = make_uint2((unsigned)l[0] | ((unsigned)l[1] << 16),
                                    (unsigned)l[2] | ((unsigned)l[3] << 16));
    }
    return;
  }
  const int kss[3] = {91, 481, 1501};
  const float sg[3] = {15.f, 80.f, 250.f};
  int ks = kss[y];
  float sigma = sg[y];
  int r = blockIdx.x;
  int p = ks >> 1;
  float ctr = (float)(ks - 1) * 0.5f;
  __shared__ float red[256];
  __shared__ float row[IMN];
  float loc = 0.f;
  for (int t = tid; t < ks; t += 256) {
    float x = ((float)t - ctr) / sigma;
    loc += expf(-0.5f * x * x);
  }
  red[tid] = loc;
  __syncthreads();
  for (int o = 128; o > 0; o >>= 1) {
    if (tid < o) red[tid] += red[tid + o];
    __syncthreads();
  }
  float inv = 1.f / red[0];
  for (int i2 = tid; i2 < IMN; i2 += 256) row[i2] = 0.f;
  __syncthreads();
  for (int t = tid; t < ks; t += 256) {
    float x = ((float)t - ctr) / sigma;
    float v = expf(-0.5f * x * x) * inv;
    int q = r + t - p;
    int j = q < 0 ? -q : (q > IMN - 1 ? 2 * (IMN - 1) - q : q);
    atomicAdd(&row[j], v);
  }
  __syncthreads();
  for (int i2 = tid; i2 < IMN; i2 += 256)
    WF[(size_t)y * IMGSZ + (size_t)r * IMN + i2] = f16_bits(row[i2] * 256.f);
}

// ---------------------------------------------------------------------------
// f16 MFMA GEMM (A x W'), 128x128 tile, 32x32x16_f16, wave 64x64.
// EXACT round-10/12 gemm (best measured: 58.3us/gemm; k-loop is closed -- 4
//   structurally different schedules all land 61-67us pre-f16; latency floor).
// Band-limited K loop (exact; see prep_k note).
// Structure lessons kept: (256,4) reg-staging (r3: (256,6)+no-barrier spills;
//   r5: A-direct regresses; r2/r8: gload_lds/counted-vmcnt neutral-worse).
//   LDS linear [128][32] + both-sides XOR swizzle (r4-verified):
//   phys_slot = slot ^ ((row>>1)&3) at ds_write AND ds_read.
// EPI=0: A = imgF[i], B = W'[s]; out OH[z] = f16 U' = 256*U, transposed.
// EPI=1: A = UtH[z],  B = W'[s]; out LB16 = f16 log(max(acc*2^-16, eps)).
template <int EPI>
__global__ __launch_bounds__(256, 4) void gemm_pass(
    const u16* __restrict__ AH, const u16* __restrict__ WF,
    u16* __restrict__ OH, u16* __restrict__ LB16, int sBase, int outByZ, int rmw) {
  __shared__ u16 smem[2 * 128 * 32 + 256];  // 16896 B (B tiles 16384; epi scratch 16896)
  u16* Af = smem;
  u16* Bf = smem + 128 * 32;
  int z = blockIdx.z;
  int zs = z / 6;
  int s = (gridDim.z >= 18) ? (sBase + 2 - zs) : (sBase + zs);  // heavy-first
  int i = z - zs * 6;
  const u16* Ag = AH + (size_t)(EPI == 0 ? i : z) * IMGSZ;
  const u16* Bg = WF + (size_t)s * IMGSZ;
  int bm = blockIdx.y * 128, bn = blockIdx.x * 128;
  int tid = threadIdx.x;
  int lane = tid & 63, w = tid >> 6;
  int wm = (w >> 1) * 64, wn = (w & 1) * 64;
  int lrow = lane & 31, lh = lane >> 5;
  int sig = (lrow >> 1) & 3;              // frag-read swizzle key
  int tr = tid >> 2;                      // staging row 0..63 (and +64)
  int tc = (tid & 3) * 8;                 // linear global col offset (u16)
  int sslot = ((tid & 3) ^ ((tr >> 1) & 3)) * 8;  // swizzled LDS slot offset
  floatx16 acc[2][2] = {};

  // Band-limited K window (exact: W' is 0.0 outside).
  int p = (s == 0) ? 45 : (s == 1) ? 240 : 750;
  int klo = bn - p;
  klo = (klo < 0 ? 0 : klo) & ~31;
  int khi = bn + 128 + p;
  if (khi > IMN) khi = IMN;

  for (int k0 = klo; k0 < khi; k0 += 32) {
    uint4 a0 = *(const uint4*)&Ag[(size_t)(bm + tr) * IMN + k0 + tc];
    uint4 a1 = *(const uint4*)&Ag[(size_t)(bm + tr + 64) * IMN + k0 + tc];
    uint4 b0 = *(const uint4*)&Bg[(size_t)(bn + tr) * IMN + k0 + tc];
    uint4 b1 = *(const uint4*)&Bg[(size_t)(bn + tr + 64) * IMN + k0 + tc];
    *(uint4*)&Af[tr * 32 + sslot] = a0;
    *(uint4*)&Af[(tr + 64) * 32 + sslot] = a1;
    *(uint4*)&Bf[tr * 32 + sslot] = b0;
    *(uint4*)&Bf[(tr + 64) * 32 + sslot] = b1;
    __syncthreads();
#pragma unroll
    for (int kk = 0; kk < 32; kk += 16) {
      int sl = (kk >> 3) + lh;            // logical 16B slot 0..3
      int so = ((sl ^ sig) * 8);          // swizzled read offset (u16)
      half8 ah[2], bh[2];
#pragma unroll
      for (int mt = 0; mt < 2; mt++)
        ah[mt] = *(const half8*)&Af[(wm + mt * 32 + lrow) * 32 + so];
#pragma unroll
      for (int nt2 = 0; nt2 < 2; nt2++)
        bh[nt2] = *(const half8*)&Bf[(wn + nt2 * 32 + lrow) * 32 + so];
#pragma unroll
      for (int mt = 0; mt < 2; mt++)
#pragma unroll
        for (int nt2 = 0; nt2 < 2; nt2++)
          acc[mt][nt2] = __builtin_amdgcn_mfma_f32_32x32x16_f16(ah[mt], bh[nt2], acc[mt][nt2], 0, 0, 0);
    }
    __syncthreads();
  }

  // Epilogue: per-wave 32x32 LDS transpose (stride 33), coalesced row stores.
  // C/D: col(n)=lane&31, row(m)=(reg&3)+8*(reg>>2)+4*(lane>>5).
  float* lf = (float*)smem + w * 1056;  // 4 x 4224 B = 16896 B total
#pragma unroll
  for (int mt = 0; mt < 2; mt++)
#pragma unroll
    for (int nt = 0; nt < 2; nt++) {
#pragma unroll
      for (int rq = 0; rq < 4; rq++)
#pragma unroll
        for (int e = 0; e < 4; e++)
          lf[lrow * 33 + rq * 8 + lh * 4 + e] = acc[mt][nt][rq * 4 + e];
      __syncthreads();
#pragma unroll
      for (int p4 = 0; p4 < 4; p4++) {
        int rl = p4 * 8 + (lane >> 3);
        int cl = (lane & 7) * 4;
        float v0 = lf[rl * 33 + cl + 0];
        float v1 = lf[rl * 33 + cl + 1];
        float v2 = lf[rl * 33 + cl + 2];
        float v3 = lf[rl * 33 + cl + 3];
        int gn = bn + wn + nt * 32 + rl;  // output row
        int gm = bm + wm + mt * 32 + cl;  // output col
        if (EPI == 0) {
          // acc IS U' = 256*U; store f16 (values in [0.256, 256]).
          size_t go = (size_t)z * IMGSZ + (size_t)gn * IMN + gm;  // keep plane offset!
          *(uint2*)&OH[go] = make_uint2(
              (unsigned)f16_bits(v0) | ((unsigned)f16_bits(v1) << 16),
              (unsigned)f16_bits(v2) | ((unsigned)f16_bits(v3) << 16));
        } else {
          // acc = 65536*blur2; un-scale exactly (pow2), log, store f16.
          const float us = 0x1p-16f;
          size_t go = (size_t)(outByZ ? z : i) * IMGSZ + (size_t)gn * IMN + gm;
          float r0 = logf(fmaxf(v0 * us, EPSV));
          float r1 = logf(fmaxf(v1 * us, EPSV));
          float r2 = logf(fmaxf(v2 * us, EPSV));
          float r3 = logf(fmaxf(v3 * us, EPSV));
          if (rmw) {  // t2 fallback: accumulate in f16 (tolerance-safe)
            uint2 pa = *(const uint2*)&LB16[go];
            float o4[4];
            unp4(pa, o4);
            r0 += o4[0]; r1 += o4[1]; r2 += o4[2]; r3 += o4[3];
          }
          *(uint2*)&LB16[go] = make_uint2(
              (unsigned)f16_bits(r0) | ((unsigned)f16_bits(r1) << 16),
              (unsigned)f16_bits(r2) | ((unsigned)f16_bits(r3) << 16));
        }
      }
      __syncthreads();
    }
}

// ---------------------------------------------------------------------------
// Vectorized 4-pixel chunks (G13): uint2 f16 lb/LI loads, NO logf (LI is
// precomputed f16 log(max(inp,eps)) from prep_k).  refl/illum = out+3 ->
// 12B offset: stores MUST be scalar dwords (round-9 float4 there = GPU fault).
// ROUND-15 ENDING RULE (4-point A/B, rounds 10/11/12/14): the finale MUST be
// plain pd/ps partial stores + separate tiny stage2 dispatch.  Any per-block
// global float-atomic finale (with OR without fence) collapses this kernel
// to ~170-182us (VGPR 16-20, VALUBusy ~3.5% -- stalled crawl).  Do not
// re-fuse the reduction.
__global__ __launch_bounds__(256) void loss_stage1_k(const u16* __restrict__ li,
                                                     const u16* __restrict__ lb, int three,
                                                     float* __restrict__ refl,
                                                     float* __restrict__ illum,
                                                     float* __restrict__ pd,
                                                     float* __restrict__ ps) {
  const int S = NIMG * IMGSZ;
  const int NCH = S >> 2;
  const int stride = NB1 * 256;
  const float third = 1.f / 3.f;
  float sd = 0.f, ss = 0.f;
  for (int c = blockIdx.x * 256 + threadIdx.x; c < NCH; c += stride) {
    int i = c << 2;
    int col = i & (IMN - 1);            // multiple of 4
    int row = (i >> 10) & (IMN - 1);
    bool hR = col < (IMN - 4);
    bool hD = row < (IMN - 1);
    float sum[5];
    {
      float t0[4];
      unp4(*(const uint2*)&lb[i], t0);
      sum[0] = t0[0]; sum[1] = t0[1]; sum[2] = t0[2]; sum[3] = t0[3];
      sum[4] = hR ? f16_val(lb[i + 4]) : 0.f;
      if (three) {
        float t1[4], t2[4];
        unp4(*(const uint2*)&lb[i + S], t1);
        unp4(*(const uint2*)&lb[i + 2 * S], t2);
#pragma unroll
        for (int j = 0; j < 4; j++) sum[j] += t1[j] + t2[j];
        if (hR) sum[4] += f16_val(lb[i + 4 + S]) + f16_val(lb[i + 4 + 2 * S]);
      }
    }
    float Iv[5], Rv[5], LIv[4];
#pragma unroll
    for (int j = 0; j < 5; j++) Iv[j] = sum[j] * third;
    unp4(*(const uint2*)&li[i], LIv);
#pragma unroll
    for (int j = 0; j < 4; j++) Rv[j] = LIv[j] - Iv[j];
    if (hR) Rv[4] = f16_val(li[i + 4]) - Iv[4];
#pragma unroll
    for (int j = 0; j < 4; j++) {  // scalar stores: refl/illum are 12B-offset
      refl[i + j] = Rv[j];
      illum[i + j] = Iv[j];
    }
#pragma unroll
    for (int j = 0; j < 3; j++) {
      sd += fabsf(Rv[j] - Rv[j + 1]);
      ss += fabsf(Iv[j] - Iv[j + 1]);
    }
    if (hR) {
      sd += fabsf(Rv[3] - Rv[4]);
      ss += fabsf(Iv[3] - Iv[4]);
    }
    if (hD) {
      int ib = i + IMN;
      float sb[4];
      {
        float t0[4];
        unp4(*(const uint2*)&lb[ib], t0);
        sb[0] = t0[0]; sb[1] = t0[1]; sb[2] = t0[2]; sb[3] = t0[3];
        if (three) {
          float t1[4], t2[4];
          unp4(*(const uint2*)&lb[ib + S], t1);
          unp4(*(const uint2*)&lb[ib + 2 * S], t2);
#pragma unroll
          for (int j = 0; j < 4; j++) sb[j] += t1[j] + t2[j];
        }
      }
      float LBv[4];
      unp4(*(const uint2*)&li[ib], LBv);
#pragma unroll
      for (int j = 0; j < 4; j++) {
        float Ib = sb[j] * third;
        float Rb = LBv[j] - Ib;
        sd += fabsf(Rv[j] - Rb);
        ss += fabsf(Iv[j] - Ib);
      }
    }
  }
  for (int o = 32; o > 0; o >>= 1) {
    sd += __shfl_down(sd, o);
    ss += __shfl_down(ss, o);
  }
  __shared__ float rsd[4], rss[4];
  int lane = threadIdx.x & 63, w = threadIdx.x >> 6;
  if (lane == 0) { rsd[w] = sd; rss[w] = ss; }
  __syncthreads();
  if (threadIdx.x == 0) {
    pd[blockIdx.x] = rsd[0] + rsd[1] + rsd[2] + rsd[3];
    ps[blockIdx.x] = rss[0] + rss[1] + rss[2] + rss[3];
  }
}

__global__ __launch_bounds__(256) void loss_stage2_k(const float* __restrict__ pd,
                                                     const float* __restrict__ ps,
                                                     float* __restrict__ out) {
  float sd = 0.f, ss = 0.f;
  for (int i = threadIdx.x; i < NB1; i += 256) {
    sd += pd[i];
    ss += ps[i];
  }
  for (int o = 32; o > 0; o >>= 1) {
    sd += __shfl_down(sd, o);
    ss += __shfl_down(ss, o);
  }
  __shared__ float rsd[4], rss[4];
  int lane = threadIdx.x & 63, w = threadIdx.x >> 6;
  if (lane == 0) { rsd[w] = sd; rss[w] = ss; }
  __syncthreads();
  if (threadIdx.x == 0) {
    float tsd = rsd[0] + rsd[1] + rsd[2] + rsd[3];
    float tss = rss[0] + rss[1] + rss[2] + rss[3];
    const float sc = 1.f / 6285312.f;  // 2*3*1024*1023
    out[0] = tss * sc;
    out[1] = tsd * sc;
    out[2] = tss * sc;
  }
}

// ---------------------------------------------------------------------------
extern "C" void kernel_launch(void* const* d_in, const int* in_sizes, int n_in,
                              void* d_out, int out_size, void* d_ws, size_t ws_size,
                              hipStream_t stream) {
  const float* inp = (const float*)d_in[0];
  float* out = (float*)d_out;
  float* refl = out + 3;
  float* illum = refl + (size_t)NIMG * IMGSZ;

  char* p = (char*)d_ws;
  float* pd = (float*)p;                    // NB1 partials (sd)
  float* ps = pd + NB1;                     // NB1 partials (ss); 32KB
  p += 32768;
  u16* WF = (u16*)p;                        p += (size_t)3 * IMGSZ * 2;
  u16* imgF = (u16*)p;                      p += (size_t)NIMG * IMGSZ * 2;
  u16* logI = (u16*)p;                      p += (size_t)NIMG * IMGSZ * 2;
  size_t fixed = (size_t)(p - (char*)d_ws);
  // Tier1 (z=18, one dispatch/pass): Ut 18 f16 planes (36 MB) + LB 18 f16
  // (36 MB).  Total ~102 MB; ws_size >= 132 MB proven by rounds 0-1.
  size_t needT1 = fixed + (size_t)18 * IMGSZ * 2 + (size_t)18 * IMGSZ * 2;
  bool t1 = ws_size >= needT1;
  int nz = t1 ? 18 : 6;
  u16* UtH = (u16*)p;                       p += (size_t)nz * IMGSZ * 2;
  u16* LB = (u16*)p;  // t1: 18 f16 log-blur planes; t2: 6-plane f16 accumulator

  prep_k<<<dim3(1024, 4), 256, 0, stream>>>(inp, imgF, logI, WF);

  if (t1) {
    dim3 g(8, 8, 18);
    gemm_pass<0><<<g, 256, 0, stream>>>(imgF, WF, UtH, nullptr, 0, 1, 0);
    gemm_pass<1><<<g, 256, 0, stream>>>(UtH, WF, nullptr, LB, 0, 1, 0);
  } else {
    dim3 g(8, 8, 6);
    for (int s = 0; s < 3; s++) {
      gemm_pass<0><<<g, 256, 0, stream>>>(imgF, WF, UtH, nullptr, s, 0, 0);
      gemm_pass<1><<<g, 256, 0, stream>>>(UtH, WF, nullptr, LB, s, 0, s > 0);
    }
  }
  loss_stage1_k<<<NB1, 256, 0, stream>>>(logI, LB, t1 ? 1 : 0, refl, illum, pd, ps);
  loss_stage2_k<<<1, 256, 0, stream>>>(pd, ps, out);
}

// Round 16
// 216.770 us; speedup vs baseline: 1.6831x; 1.0327x over previous
//
#include <hip/hip_runtime.h>
#include <math.h>

#define IMN 1024
#define IMGSZ (IMN * IMN)
#define NIMG 6
#define EPSV 0.001f
#define NB1 4096

typedef unsigned short u16;
typedef _Float16 f16;
typedef __attribute__((ext_vector_type(8))) _Float16 half8;   // 8 f16 = 4 VGPRs
typedef __attribute__((ext_vector_type(16))) float floatx16;  // 32x32 C/D

__device__ __forceinline__ u16 f16_bits(float v) {
  union { f16 h; u16 b; } u;
  u.h = (f16)v;  // v_cvt_f16_f32, RNE
  return u.b;
}
__device__ __forceinline__ float f16_val(u16 b) {
  union { f16 h; u16 b2; } u;
  u.b2 = b;
  return (float)u.h;
}
__device__ __forceinline__ void unp4(uint2 v, float* o) {
  o[0] = f16_val((u16)(v.x & 0xffff));
  o[1] = f16_val((u16)(v.x >> 16));
  o[2] = f16_val((u16)(v.y & 0xffff));
  o[3] = f16_val((u16)(v.y >> 16));
}

// ---------------------------------------------------------------------------
// ONE prep dispatch (proven r12/r15): taps+W inline, split_img + logI.
__global__ __launch_bounds__(256) void prep_k(const float* __restrict__ inp,
                                              u16* __restrict__ H,
                                              u16* __restrict__ LI,
                                              u16* __restrict__ WF) {
  int y = blockIdx.y;
  int tid = threadIdx.x;
  if (y == 3) {
#pragma unroll
    for (int r2 = 0; r2 < 6; r2++) {
      int i4 = ((r2 * 1024 + blockIdx.x) << 10) + tid * 4;
      float4 v = *(const float4*)&inp[i4];
      float x[4] = {v.x, v.y, v.z, v.w};
      u16 h[4], l[4];
#pragma unroll
      for (int e = 0; e < 4; e++) {
        h[e] = f16_bits(fminf(fmaxf(x[e], EPSV), 1.f));
        l[e] = f16_bits(logf(fmaxf(x[e], EPSV)));
      }
      *(uint2*)&H[i4] = make_uint2((unsigned)h[0] | ((unsigned)h[1] << 16),
                                   (unsigned)h[2] | ((unsigned)h[3] << 16));
      *(uint2*)&LI[i4] = make_uint2((unsigned)l[0] | ((unsigned)l[1] << 16),
                                    (unsigned)l[2] | ((unsigned)l[3] << 16));
    }
    return;
  }
  const int kss[3] = {91, 481, 1501};
  const float sg[3] = {15.f, 80.f, 250.f};
  int ks = kss[y];
  float sigma = sg[y];
  int r = blockIdx.x;
  int p = ks >> 1;
  float ctr = (float)(ks - 1) * 0.5f;
  __shared__ float red[256];
  __shared__ float row[IMN];
  float loc = 0.f;
  for (int t = tid; t < ks; t += 256) {
    float x = ((float)t - ctr) / sigma;
    loc += expf(-0.5f * x * x);
  }
  red[tid] = loc;
  __syncthreads();
  for (int o = 128; o > 0; o >>= 1) {
    if (tid < o) red[tid] += red[tid + o];
    __syncthreads();
  }
  float inv = 1.f / red[0];
  for (int i2 = tid; i2 < IMN; i2 += 256) row[i2] = 0.f;
  __syncthreads();
  for (int t = tid; t < ks; t += 256) {
    float x = ((float)t - ctr) / sigma;
    float v = expf(-0.5f * x * x) * inv;
    int q = r + t - p;
    int j = q < 0 ? -q : (q > IMN - 1 ? 2 * (IMN - 1) - q : q);
    atomicAdd(&row[j], v);
  }
  __syncthreads();
  for (int i2 = tid; i2 < IMN; i2 += 256)
    WF[(size_t)y * IMGSZ + (size_t)r * IMN + i2] = f16_bits(row[i2] * 256.f);
}

// ---------------------------------------------------------------------------
// f16 MFMA GEMM, ROUND-16: TWO-IMAGE PAIRING.  The closed 60.5us gemm is
// latency/convoy-bound: 21216 block-k-steps / 256 CU = 1756 cyc/step/CU
// while issue-work per step is a few hundred cycles -- chains don't overlap
// (rounds 2/3/5/8: rescheduling nulls).  This round adds ILP WITHIN the
// chain instead: each block computes images (2p, 2p+1) sharing one W panel.
// Per k-step: stage A0+A1+B (B amortized 2x), 2 independent MFMA streams;
// total steps HALVE (10608); barriers per output halve.  Grid (8,8,3*nS).
// acc0+acc1 = 128 VGPR -> (256,2) budget 256; epilogue #pragma unroll im
// keeps acc indexing compile-time (rule #20: no runtime ext_vector index).
// Band-limited K loop (exact: W' is 0.0 outside support).
// LDS [128][32] x {A0,A1,B} linear + both-sides XOR swizzle (r4-verified).
// Plane map: uplane(s,i) = t1 ? (2-s)*6+i : i  (matches loss1's lb[i+k*S]).
// EPI=0: A = imgF[i], B = W'[s]; out OH[uplane] = f16 U' = 256*U, transposed.
// EPI=1: A = UtH[uplane], B = W'[s]; out LB16[uplane] = f16 log(acc*2^-16).
template <int EPI>
__global__ __launch_bounds__(256, 2) void gemm_pair(
    const u16* __restrict__ AH, const u16* __restrict__ WF,
    u16* __restrict__ OH, u16* __restrict__ LB16, int sBase, int outByZ, int rmw) {
  __shared__ u16 smem[3 * 128 * 32];  // 24576 B: A0, A1, B
  u16* A0 = smem;
  u16* A1 = smem + 4096;
  u16* Bf = smem + 8192;
  int z = blockIdx.z;
  int s = (gridDim.z >= 9) ? (2 - z / 3) : sBase;  // heavy-first in t1
  int pr = z - (z / 3) * 3;
  int i0 = 2 * pr, i1 = i0 + 1;
  int zp0 = (2 - s) * 6 + i0;
  int up0 = outByZ ? zp0 : i0;
  int up1 = up0 + 1;                  // zp1 = zp0+1, i1 = i0+1 in both modes
  const u16* Ag0 = AH + (size_t)(EPI == 0 ? i0 : up0) * IMGSZ;
  const u16* Ag1 = AH + (size_t)(EPI == 0 ? i1 : up1) * IMGSZ;
  const u16* Bg = WF + (size_t)s * IMGSZ;
  int bm = blockIdx.y * 128, bn = blockIdx.x * 128;
  int tid = threadIdx.x;
  int lane = tid & 63, w = tid >> 6;
  int wm = (w >> 1) * 64, wn = (w & 1) * 64;
  int lrow = lane & 31, lh = lane >> 5;
  int sig = (lrow >> 1) & 3;              // frag-read swizzle key
  int tr = tid >> 2;                      // staging row 0..63 (and +64)
  int tc = (tid & 3) * 8;                 // linear global col offset (u16)
  int sslot = ((tid & 3) ^ ((tr >> 1) & 3)) * 8;  // swizzled LDS slot offset
  floatx16 acc0[2][2] = {};
  floatx16 acc1[2][2] = {};

  // Band-limited K window (exact: W' is 0.0 outside).
  int p = (s == 0) ? 45 : (s == 1) ? 240 : 750;
  int klo = bn - p;
  klo = (klo < 0 ? 0 : klo) & ~31;
  int khi = bn + 128 + p;
  if (khi > IMN) khi = IMN;

  for (int k0 = klo; k0 < khi; k0 += 32) {
    uint4 a00 = *(const uint4*)&Ag0[(size_t)(bm + tr) * IMN + k0 + tc];
    uint4 a01 = *(const uint4*)&Ag0[(size_t)(bm + tr + 64) * IMN + k0 + tc];
    uint4 a10 = *(const uint4*)&Ag1[(size_t)(bm + tr) * IMN + k0 + tc];
    uint4 a11 = *(const uint4*)&Ag1[(size_t)(bm + tr + 64) * IMN + k0 + tc];
    uint4 b0 = *(const uint4*)&Bg[(size_t)(bn + tr) * IMN + k0 + tc];
    uint4 b1 = *(const uint4*)&Bg[(size_t)(bn + tr + 64) * IMN + k0 + tc];
    *(uint4*)&A0[tr * 32 + sslot] = a00;
    *(uint4*)&A0[(tr + 64) * 32 + sslot] = a01;
    *(uint4*)&A1[tr * 32 + sslot] = a10;
    *(uint4*)&A1[(tr + 64) * 32 + sslot] = a11;
    *(uint4*)&Bf[tr * 32 + sslot] = b0;
    *(uint4*)&Bf[(tr + 64) * 32 + sslot] = b1;
    __syncthreads();
#pragma unroll
    for (int kk = 0; kk < 32; kk += 16) {
      int sl = (kk >> 3) + lh;            // logical 16B slot 0..3
      int so = ((sl ^ sig) * 8);          // swizzled read offset (u16)
      half8 ah0[2], ah1[2], bh[2];
#pragma unroll
      for (int mt = 0; mt < 2; mt++) {
        int ro = (wm + mt * 32 + lrow) * 32 + so;
        ah0[mt] = *(const half8*)&A0[ro];
        ah1[mt] = *(const half8*)&A1[ro];
      }
#pragma unroll
      for (int nt2 = 0; nt2 < 2; nt2++)
        bh[nt2] = *(const half8*)&Bf[(wn + nt2 * 32 + lrow) * 32 + so];
#pragma unroll
      for (int mt = 0; mt < 2; mt++)
#pragma unroll
        for (int nt2 = 0; nt2 < 2; nt2++) {
          acc0[mt][nt2] = __builtin_amdgcn_mfma_f32_32x32x16_f16(ah0[mt], bh[nt2], acc0[mt][nt2], 0, 0, 0);
          acc1[mt][nt2] = __builtin_amdgcn_mfma_f32_32x32x16_f16(ah1[mt], bh[nt2], acc1[mt][nt2], 0, 0, 0);
        }
    }
    __syncthreads();
  }

  // Epilogue (r10-proven pattern, run twice -- im unrolled so acc indexing
  // is compile-time, rule #20): per-wave 32x32 LDS transpose (stride 33),
  // coalesced row stores.  C/D: col(n)=lane&31, row(m)=(reg&3)+8*(reg>>2)+4*(lane>>5).
  float* lf = (float*)smem + w * 1056;  // 4 x 4224 B = 16896 <= 24576
#pragma unroll
  for (int im = 0; im < 2; im++) {
    size_t uplane = (size_t)(im == 0 ? up0 : up1);
#pragma unroll
    for (int mt = 0; mt < 2; mt++)
#pragma unroll
      for (int nt = 0; nt < 2; nt++) {
#pragma unroll
        for (int rq = 0; rq < 4; rq++)
#pragma unroll
          for (int e = 0; e < 4; e++)
            lf[lrow * 33 + rq * 8 + lh * 4 + e] =
                (im == 0 ? acc0[mt][nt][rq * 4 + e] : acc1[mt][nt][rq * 4 + e]);
        __syncthreads();
#pragma unroll
        for (int p4 = 0; p4 < 4; p4++) {
          int rl = p4 * 8 + (lane >> 3);
          int cl = (lane & 7) * 4;
          float v0 = lf[rl * 33 + cl + 0];
          float v1 = lf[rl * 33 + cl + 1];
          float v2 = lf[rl * 33 + cl + 2];
          float v3 = lf[rl * 33 + cl + 3];
          int gn = bn + wn + nt * 32 + rl;  // output row
          int gm = bm + wm + mt * 32 + cl;  // output col
          if (EPI == 0) {
            // acc IS U' = 256*U; store f16 (values in [0.256, 256]).
            size_t go = uplane * IMGSZ + (size_t)gn * IMN + gm;
            *(uint2*)&OH[go] = make_uint2(
                (unsigned)f16_bits(v0) | ((unsigned)f16_bits(v1) << 16),
                (unsigned)f16_bits(v2) | ((unsigned)f16_bits(v3) << 16));
          } else {
            // acc = 65536*blur2; un-scale exactly (pow2), log, store f16.
            const float us = 0x1p-16f;
            size_t go = uplane * IMGSZ + (size_t)gn * IMN + gm;
            float r0 = logf(fmaxf(v0 * us, EPSV));
            float r1 = logf(fmaxf(v1 * us, EPSV));
            float r2 = logf(fmaxf(v2 * us, EPSV));
            float r3 = logf(fmaxf(v3 * us, EPSV));
            if (rmw) {  // t2 fallback: accumulate in f16 (tolerance-safe)
              uint2 pa = *(const uint2*)&LB16[go];
              float o4[4];
              unp4(pa, o4);
              r0 += o4[0]; r1 += o4[1]; r2 += o4[2]; r3 += o4[3];
            }
            *(uint2*)&LB16[go] = make_uint2(
                (unsigned)f16_bits(r0) | ((unsigned)f16_bits(r1) << 16),
                (unsigned)f16_bits(r2) | ((unsigned)f16_bits(r3) << 16));
          }
        }
        __syncthreads();
      }
  }
}

// ---------------------------------------------------------------------------
// Vectorized 4-pixel chunks (G13): uint2 f16 lb/LI loads, NO logf (LI is
// precomputed f16 log(max(inp,eps)) from prep_k).  refl/illum = out+3 ->
// 12B offset: stores MUST be scalar dwords (round-9 float4 there = GPU fault).
// ENDING RULE (4-point A/B, rounds 10/11/12/14): plain pd/ps partial stores
// + tiny stage2 dispatch.  Any per-block global float-atomic finale (with OR
// without fence) collapses this kernel to ~170-182us.  Do not re-fuse.
__global__ __launch_bounds__(256) void loss_stage1_k(const u16* __restrict__ li,
                                                     const u16* __restrict__ lb, int three,
                                                     float* __restrict__ refl,
                                                     float* __restrict__ illum,
                                                     float* __restrict__ pd,
                                                     float* __restrict__ ps) {
  const int S = NIMG * IMGSZ;
  const int NCH = S >> 2;
  const int stride = NB1 * 256;
  const float third = 1.f / 3.f;
  float sd = 0.f, ss = 0.f;
  for (int c = blockIdx.x * 256 + threadIdx.x; c < NCH; c += stride) {
    int i = c << 2;
    int col = i & (IMN - 1);            // multiple of 4
    int row = (i >> 10) & (IMN - 1);
    bool hR = col < (IMN - 4);
    bool hD = row < (IMN - 1);
    float sum[5];
    {
      float t0[4];
      unp4(*(const uint2*)&lb[i], t0);
      sum[0] = t0[0]; sum[1] = t0[1]; sum[2] = t0[2]; sum[3] = t0[3];
      sum[4] = hR ? f16_val(lb[i + 4]) : 0.f;
      if (three) {
        float t1[4], t2[4];
        unp4(*(const uint2*)&lb[i + S], t1);
        unp4(*(const uint2*)&lb[i + 2 * S], t2);
#pragma unroll
        for (int j = 0; j < 4; j++) sum[j] += t1[j] + t2[j];
        if (hR) sum[4] += f16_val(lb[i + 4 + S]) + f16_val(lb[i + 4 + 2 * S]);
      }
    }
    float Iv[5], Rv[5], LIv[4];
#pragma unroll
    for (int j = 0; j < 5; j++) Iv[j] = sum[j] * third;
    unp4(*(const uint2*)&li[i], LIv);
#pragma unroll
    for (int j = 0; j < 4; j++) Rv[j] = LIv[j] - Iv[j];
    if (hR) Rv[4] = f16_val(li[i + 4]) - Iv[4];
#pragma unroll
    for (int j = 0; j < 4; j++) {  // scalar stores: refl/illum are 12B-offset
      refl[i + j] = Rv[j];
      illum[i + j] = Iv[j];
    }
#pragma unroll
    for (int j = 0; j < 3; j++) {
      sd += fabsf(Rv[j] - Rv[j + 1]);
      ss += fabsf(Iv[j] - Iv[j + 1]);
    }
    if (hR) {
      sd += fabsf(Rv[3] - Rv[4]);
      ss += fabsf(Iv[3] - Iv[4]);
    }
    if (hD) {
      int ib = i + IMN;
      float sb[4];
      {
        float t0[4];
        unp4(*(const uint2*)&lb[ib], t0);
        sb[0] = t0[0]; sb[1] = t0[1]; sb[2] = t0[2]; sb[3] = t0[3];
        if (three) {
          float t1[4], t2[4];
          unp4(*(const uint2*)&lb[ib + S], t1);
          unp4(*(const uint2*)&lb[ib + 2 * S], t2);
#pragma unroll
          for (int j = 0; j < 4; j++) sb[j] += t1[j] + t2[j];
        }
      }
      float LBv[4];
      unp4(*(const uint2*)&li[ib], LBv);
#pragma unroll
      for (int j = 0; j < 4; j++) {
        float Ib = sb[j] * third;
        float Rb = LBv[j] - Ib;
        sd += fabsf(Rv[j] - Rb);
        ss += fabsf(Iv[j] - Ib);
      }
    }
  }
  for (int o = 32; o > 0; o >>= 1) {
    sd += __shfl_down(sd, o);
    ss += __shfl_down(ss, o);
  }
  __shared__ float rsd[4], rss[4];
  int lane = threadIdx.x & 63, w = threadIdx.x >> 6;
  if (lane == 0) { rsd[w] = sd; rss[w] = ss; }
  __syncthreads();
  if (threadIdx.x == 0) {
    pd[blockIdx.x] = rsd[0] + rsd[1] + rsd[2] + rsd[3];
    ps[blockIdx.x] = rss[0] + rss[1] + rss[2] + rss[3];
  }
}

__global__ __launch_bounds__(256) void loss_stage2_k(const float* __restrict__ pd,
                                                     const float* __restrict__ ps,
                                                     float* __restrict__ out) {
  float sd = 0.f, ss = 0.f;
  for (int i = threadIdx.x; i < NB1; i += 256) {
    sd += pd[i];
    ss += ps[i];
  }
  for (int o = 32; o > 0; o >>= 1) {
    sd += __shfl_down(sd, o);
    ss += __shfl_down(ss, o);
  }
  __shared__ float rsd[4], rss[4];
  int lane = threadIdx.x & 63, w = threadIdx.x >> 6;
  if (lane == 0) { rsd[w] = sd; rss[w] = ss; }
  __syncthreads();
  if (threadIdx.x == 0) {
    float tsd = rsd[0] + rsd[1] + rsd[2] + rsd[3];
    float tss = rss[0] + rss[1] + rss[2] + rss[3];
    const float sc = 1.f / 6285312.f;  // 2*3*1024*1023
    out[0] = tss * sc;
    out[1] = tsd * sc;
    out[2] = tss * sc;
  }
}

// ---------------------------------------------------------------------------
extern "C" void kernel_launch(void* const* d_in, const int* in_sizes, int n_in,
                              void* d_out, int out_size, void* d_ws, size_t ws_size,
                              hipStream_t stream) {
  const float* inp = (const float*)d_in[0];
  float* out = (float*)d_out;
  float* refl = out + 3;
  float* illum = refl + (size_t)NIMG * IMGSZ;

  char* p = (char*)d_ws;
  float* pd = (float*)p;                    // NB1 partials (sd)
  float* ps = pd + NB1;                     // NB1 partials (ss); 32KB
  p += 32768;
  u16* WF = (u16*)p;                        p += (size_t)3 * IMGSZ * 2;
  u16* imgF = (u16*)p;                      p += (size_t)NIMG * IMGSZ * 2;
  u16* logI = (u16*)p;                      p += (size_t)NIMG * IMGSZ * 2;
  size_t fixed = (size_t)(p - (char*)d_ws);
  // Tier1: Ut 18 f16 planes (36 MB) + LB 18 f16 (36 MB).  Total ~102 MB;
  // ws_size >= 132 MB proven by rounds 0-1.
  size_t needT1 = fixed + (size_t)18 * IMGSZ * 2 + (size_t)18 * IMGSZ * 2;
  bool t1 = ws_size >= needT1;
  int nz = t1 ? 18 : 6;
  u16* UtH = (u16*)p;                       p += (size_t)nz * IMGSZ * 2;
  u16* LB = (u16*)p;  // t1: 18 f16 log-blur planes; t2: 6-plane f16 accumulator

  prep_k<<<dim3(1024, 4), 256, 0, stream>>>(inp, imgF, logI, WF);

  if (t1) {
    dim3 g(8, 8, 9);
    gemm_pair<0><<<g, 256, 0, stream>>>(imgF, WF, UtH, nullptr, 0, 1, 0);
    gemm_pair<1><<<g, 256, 0, stream>>>(UtH, WF, nullptr, LB, 0, 1, 0);
  } else {
    dim3 g(8, 8, 3);
    for (int s = 0; s < 3; s++) {
      gemm_pair<0><<<g, 256, 0, stream>>>(imgF, WF, UtH, nullptr, s, 0, 0);
      gemm_pair<1><<<g, 256, 0, stream>>>(UtH, WF, nullptr, LB, s, 0, s > 0);
    }
  }
  loss_stage1_k<<<NB1, 256, 0, stream>>>(logI, LB, t1 ? 1 : 0, refl, illum, pd, ps);
  loss_stage2_k<<<1, 256, 0, stream>>>(pd, ps, out);
}